// Round 1
// 871.101 us; speedup vs baseline: 1.0644x; 1.0644x over previous
//
#include <hip/hip_runtime.h>
#include <hip/hip_bf16.h>
#include <cstdint>

// Problem constants
#define BB 8
#define CC 512
#define HH 96
#define NN 9216      // 96*96
#define HEADS 4
#define HD 128
#define KMAX 256     // c/2

typedef unsigned short ushort_t;
typedef __attribute__((ext_vector_type(8))) short bf16x8;
typedef __attribute__((ext_vector_type(4))) float f32x4;

__device__ __forceinline__ unsigned short f2bf(float f) {
  unsigned int u = __float_as_uint(f);
  u += 0x7fffu + ((u >> 16) & 1u);   // RNE; values are finite here
  return (unsigned short)(u >> 16);
}
__device__ __forceinline__ float bf2f(unsigned short s) {
  return __uint_as_float(((unsigned int)s) << 16);
}
__device__ __forceinline__ unsigned int pk2(float lo, float hi) {
  return (unsigned int)f2bf(lo) | ((unsigned int)f2bf(hi) << 16);
}

// async global->LDS 16B: lds dest must be wave-uniform base; HW scatters lane i at +16*i
__device__ __forceinline__ void gld16(const void* g, void* l) {
  __builtin_amdgcn_global_load_lds(
      (const __attribute__((address_space(1))) unsigned int*)(uintptr_t)g,
      (__attribute__((address_space(3))) unsigned int*)(unsigned int)(uintptr_t)l,
      16, 0, 0);
}

// ---------------- rope table: cos/sin[col][kk], col = pos % 96 ----------------
__global__ void rope_table_k(float* __restrict__ rope) {
  int t = blockIdx.x * 256 + threadIdx.x;
  if (t >= HH * KMAX) return;
  int col = t >> 8;
  int kk = t & (KMAX - 1);
  float theta = powf(10000.0f, -((float)kk) / (float)KMAX);
  float ang = (float)col * theta;
  float s, c;
  sincosf(ang, &s, &c);
  rope[2 * t] = c;
  rope[2 * t + 1] = s;
}

// ---------------- W fp32 -> bf16 ----------------------------------------------
__global__ void conv_w_k(const float* __restrict__ W, unsigned short* __restrict__ Wbf) {
  int t = blockIdx.x * 256 + threadIdx.x;  // 131072 float4s
  float4 v = *(const float4*)(W + (size_t)t * 4);
  unsigned int lo = (unsigned int)f2bf(v.x) | ((unsigned int)f2bf(v.y) << 16);
  unsigned int hi = (unsigned int)f2bf(v.z) | ((unsigned int)f2bf(v.w) << 16);
  *(uint2*)(Wbf + (size_t)t * 4) = make_uint2(lo, hi);
}

// ---------------- per-batch transpose: x[b][ch][pos] fp32 -> xt[pos][ch] bf16 --
__global__ void transpose_xb_k(const float* __restrict__ x, unsigned short* __restrict__ xt,
                               int b) {
  __shared__ unsigned short T[64 * 72];  // [pos][ch], pad 8 (row 144B, 16B-aligned)
  const int pos0 = blockIdx.x * 64;
  const int ch0 = blockIdx.y * 64;
  const int tid = threadIdx.x;
#pragma unroll
  for (int i = 0; i < 4; ++i) {
    int fi = i * 256 + tid;          // 0..1023
    int ch = fi >> 4, p4 = fi & 15;  // 64 ch x 16 float4
    float4 v = *(const float4*)(x + ((size_t)b * CC + ch0 + ch) * NN + pos0 + p4 * 4);
    T[(p4 * 4 + 0) * 72 + ch] = f2bf(v.x);
    T[(p4 * 4 + 1) * 72 + ch] = f2bf(v.y);
    T[(p4 * 4 + 2) * 72 + ch] = f2bf(v.z);
    T[(p4 * 4 + 3) * 72 + ch] = f2bf(v.w);
  }
  __syncthreads();
#pragma unroll
  for (int i = 0; i < 2; ++i) {
    int s = i * 256 + tid;          // 0..511
    int p = s >> 3, cc = s & 7;     // 64 rows x 8 chunks of 16B
    uint4 u = *(const uint4*)&T[p * 72 + cc * 8];
    *(uint4*)(xt + (size_t)(pos0 + p) * CC + ch0 + cc * 8) = u;
  }
}

// ---------------- qk GEMM (MFMA bf16): C[m,j] = sum_ch xt[m,ch]*Wbf[j,ch] ------
__launch_bounds__(256)
__global__ void gemm_qk_mfma(const unsigned short* __restrict__ xt,
                             const unsigned short* __restrict__ Wbf,
                             const float* __restrict__ bqk,
                             unsigned short* __restrict__ qout,
                             unsigned short* __restrict__ kout, int b) {
  __shared__ __align__(16) unsigned short sA[128 * 64];
  __shared__ __align__(16) unsigned short sB[128 * 64];
  const int tid = threadIdx.x;
  const int wv = tid >> 6, lane = tid & 63;
  const int bn = blockIdx.x;        // 0..7 (j blocks)
  const int m0 = blockIdx.y * 128;  // pos within batch
  const int j0 = bn * 128;
  const int row = lane & 15, quad = lane >> 4;
  const int mt0 = (wv & 1) * 64, nt0 = (wv >> 1) * 64;
  f32x4 acc[4][4];
#pragma unroll
  for (int mi = 0; mi < 4; ++mi)
#pragma unroll
    for (int ni = 0; ni < 4; ++ni) acc[mi][ni] = (f32x4){0.f, 0.f, 0.f, 0.f};

  for (int kt = 0; kt < CC; kt += 64) {
#pragma unroll
    for (int it = 0; it < 4; ++it) {
      int s = it * 256 + tid;                 // LDS slot (16B units)
      int srow = s >> 3;                      // tile row 0..127
      int sc = (s & 7) ^ (srow & 7);          // swizzled chunk -> global chunk
      int ldsoff = (it * 256 + wv * 64) * 8;  // wave-uniform base (ushort units)
      gld16(xt + (size_t)(m0 + srow) * CC + kt + sc * 8, &sA[ldsoff]);
      gld16(Wbf + (size_t)(j0 + srow) * CC + kt + sc * 8, &sB[ldsoff]);
    }
    __syncthreads();
#pragma unroll
    for (int ks = 0; ks < 2; ++ks) {
      bf16x8 af[4], bf[4];
      const int chunk = (ks * 4 + quad) ^ (row & 7);
#pragma unroll
      for (int mi = 0; mi < 4; ++mi)
        af[mi] = *(const bf16x8*)&sA[((mt0 + mi * 16 + row) * 8 + chunk) * 8];
#pragma unroll
      for (int ni = 0; ni < 4; ++ni)
        bf[ni] = *(const bf16x8*)&sB[((nt0 + ni * 16 + row) * 8 + chunk) * 8];
#pragma unroll
      for (int mi = 0; mi < 4; ++mi)
#pragma unroll
        for (int ni = 0; ni < 4; ++ni)
          acc[mi][ni] = __builtin_amdgcn_mfma_f32_16x16x32_bf16(af[mi], bf[ni], acc[mi][ni], 0, 0, 0);
    }
    __syncthreads();
  }
  // epilogue: bias + elu+1, bf16 store. C/D layout: col=lane&15, row=quad*4+reg.
  unsigned short* dst = (j0 < CC) ? qout : kout;
  const int jl = (j0 & (CC - 1)) + nt0;
  float bj[4];
#pragma unroll
  for (int ni = 0; ni < 4; ++ni) bj[ni] = bqk[j0 + nt0 + ni * 16 + row];
#pragma unroll
  for (int mi = 0; mi < 4; ++mi) {
#pragma unroll
    for (int ni = 0; ni < 4; ++ni) {
#pragma unroll
      for (int r = 0; r < 4; ++r) {
        float v = acc[mi][ni][r] + bj[ni];
        v = v > 0.f ? v + 1.f : expm1f(v) + 1.f;
        int mrow = m0 + mt0 + mi * 16 + quad * 4 + r;
        dst[((size_t)b * NN + mrow) * CC + jl + ni * 16 + row] = f2bf(v);
      }
    }
  }
}

// ---------------- k_mean 2-stage over weird flat reshape ----------------------
__global__ void kmean_p1_k(const unsigned short* __restrict__ kbf, float* __restrict__ part) {
  __shared__ float red[256];
  const int seg = blockIdx.x;  // 0..17
  const int bh = blockIdx.y;   // 0..31
  const int b = bh >> 2, head = bh & 3;
  const int tid = threadIdx.x;
  const int d = tid & 127, half = tid >> 7;
  const unsigned short* base =
      kbf + ((size_t)b * NN + head * 2304 + seg * 128 + half * 64) * CC + d;
  float sum = 0.f;
  for (int pp = 0; pp < 64; ++pp) {
    const unsigned short* rp = base + (size_t)pp * CC;
    sum += bf2f(rp[0]) + bf2f(rp[128]) + bf2f(rp[256]) + bf2f(rp[384]);
  }
  red[tid] = sum;
  __syncthreads();
  if (half == 0) part[((size_t)bh * 18 + seg) * 128 + d] = red[d] + red[d + 128];
}

__global__ void kmean_p2_k(const float* __restrict__ part, float* __restrict__ kmean) {
  int idx = blockIdx.x * 256 + threadIdx.x;  // 4096
  int bh = idx >> 7, d = idx & 127;
  float s = 0.f;
#pragma unroll
  for (int i = 0; i < 18; ++i) s += part[((size_t)bh * 18 + i) * 128 + d];
  kmean[idx] = s * (1.0f / 9216.0f);
}

// ---------------- z[bh,p] = 1/(q2[bh,p,:].kmean[bh,:] + 1e-6) -----------------
__global__ void z_k(const unsigned short* __restrict__ qbf, const float* __restrict__ kmean,
                    float* __restrict__ z) {
  const int wv = threadIdx.x >> 6, lane = threadIdx.x & 63;
  const int zbase = (blockIdx.x * 4 + wv) * 8;
  const int bh = zbase / NN;
  const int p0 = zbase % NN;
  const int b = bh >> 2, head = bh & 3;
  const float km0 = kmean[bh * 128 + lane * 2];
  const float km1 = kmean[bh * 128 + lane * 2 + 1];
#pragma unroll
  for (int it = 0; it < 8; ++it) {
    const int p = p0 + it;
    const int pos = head * 2304 + (p >> 2);
    const int chb = (p & 3) * 128;
    const unsigned short* qp = qbf + ((size_t)b * NN + pos) * CC + chb + lane * 2;
    float dot = bf2f(qp[0]) * km0 + bf2f(qp[1]) * km1;
#pragma unroll
    for (int off = 1; off < 64; off <<= 1) dot += __shfl_xor(dot, off, 64);
    if (lane == 0) z[zbase + it] = 1.0f / (dot + 1e-6f);
  }
}

// ---------------- kv partials via MFMA ----------------------------------------
// kvp[s][bh][e][d] = sum_{q in seg} V[q][e] * Krope[q][d]
// q-order: q = r*2304 + t with p = 4t + r, so V[q][e] = x[b, r*128+e, head*2304+t]
// is k-contiguous (global-direct A frags, cvt fp32->bf16). Krope is built in
// registers from kbf rows (each thread owns 4 output d-rows x 8 q: the rope
// pair (re,im) IS two d-rows, so the transpose is free), then ds_write_b128
// into octet-swizzled sK[d][q] for conflict-free b128 B-frag reads.
__launch_bounds__(256, 2)
__global__ void kv_mfma_k(const unsigned short* __restrict__ kbf, const float* __restrict__ x,
                          const float* __restrict__ rope, float* __restrict__ kvp) {
  __shared__ __align__(16) unsigned short sK[128 * 64];  // [d 128][q 64], swizzled octets
  const int s = blockIdx.x;   // 0..15 (q segment)
  const int bh = blockIdx.y;  // 0..31
  const int b = bh >> 2, head = bh & 3;
  const int tid = threadIdx.x;
  const int wv = tid >> 6, lane = tid & 63;
  const int row = lane & 15, quad = lane >> 4;
  const int e0 = (wv & 1) * 64, d0 = (wv >> 1) * 64;
  const int r = s >> 2;           // p = 4t + r
  const int t0 = (s & 3) * 576;   // t range [t0, t0+576), 9 chunks of 64

  // staging role: this thread owns q-octet qg (8 q) x 4 d-rows (2 rope pairs)
  const int qg = tid & 7;
  const int dg = (tid >> 3) * 4;  // first d row (0,4,..,124)
  const unsigned short* kbase = kbf + (size_t)b * NN * CC + head * HD + dg;
  const int pairb = head * 64 + (dg >> 1);

  f32x4 acc[4][4];
#pragma unroll
  for (int mi = 0; mi < 4; ++mi)
#pragma unroll
    for (int ni = 0; ni < 4; ++ni) acc[mi][ni] = (f32x4){0.f, 0.f, 0.f, 0.f};

  for (int ck = 0; ck < 9; ++ck) {
    const int tc = t0 + ck * 64;
    // ---- issue V (A-operand) global loads early: 8 frags x 32B fp32 ----
    float4 a0[8], a1[8];
#pragma unroll
    for (int mi = 0; mi < 4; ++mi)
#pragma unroll
      for (int ks = 0; ks < 2; ++ks) {
        const float* xp = x + (size_t)(b * CC + r * 128 + e0 + mi * 16 + row) * NN +
                          head * 2304 + tc + ks * 32 + quad * 8;
        a0[mi * 2 + ks] = *(const float4*)xp;
        a1[mi * 2 + ks] = *(const float4*)(xp + 4);
      }
    // ---- K staging: rope in fp32, transpose-by-ownership, 4 b128 writes ----
    {
      int p = 4 * (tc + qg * 8) + r;
      int col = p % 96;
      float rw0[8], rw1[8], rw2[8], rw3[8];
#pragma unroll
      for (int j = 0; j < 8; ++j) {
        uint2 kv2 = *(const uint2*)(kbase + (size_t)p * CC);
        const float* rp = rope + ((size_t)col * KMAX + pairb) * 2;
        float4 cs = *(const float4*)rp;  // c0 s0 c1 s1
        float re0 = bf2f((unsigned short)(kv2.x & 0xffffu));
        float im0 = bf2f((unsigned short)(kv2.x >> 16));
        float re1 = bf2f((unsigned short)(kv2.y & 0xffffu));
        float im1 = bf2f((unsigned short)(kv2.y >> 16));
        rw0[j] = cs.x * re0 - cs.y * im0;
        rw1[j] = cs.y * re0 + cs.x * im0;
        rw2[j] = cs.z * re1 - cs.w * im1;
        rw3[j] = cs.w * re1 + cs.z * im1;
        p += 4;
        col += 4;
        col = (col >= 96) ? col - 96 : col;
      }
#pragma unroll
      for (int rr = 0; rr < 4; ++rr) {
        const float* rw = (rr == 0) ? rw0 : (rr == 1) ? rw1 : (rr == 2) ? rw2 : rw3;
        const int d = dg + rr;
        uint4 pk;
        pk.x = pk2(rw[0], rw[1]);
        pk.y = pk2(rw[2], rw[3]);
        pk.z = pk2(rw[4], rw[5]);
        pk.w = pk2(rw[6], rw[7]);
        *(uint4*)&sK[(d * 8 + (qg ^ (d & 7))) * 8] = pk;
      }
    }
    __syncthreads();
    // ---- MFMA phase ----
#pragma unroll
    for (int ks = 0; ks < 2; ++ks) {
      bf16x8 bfr[4];
#pragma unroll
      for (int ni = 0; ni < 4; ++ni) {
        const int d = d0 + ni * 16 + row;
        const int o = (ks * 4 + quad) ^ (d & 7);
        bfr[ni] = *(const bf16x8*)&sK[(d * 8 + o) * 8];
      }
#pragma unroll
      for (int mi = 0; mi < 4; ++mi) {
        const int f = mi * 2 + ks;
        union { bf16x8 v; unsigned int u[4]; } af;
        af.u[0] = pk2(a0[f].x, a0[f].y);
        af.u[1] = pk2(a0[f].z, a0[f].w);
        af.u[2] = pk2(a1[f].x, a1[f].y);
        af.u[3] = pk2(a1[f].z, a1[f].w);
#pragma unroll
        for (int ni = 0; ni < 4; ++ni)
          acc[mi][ni] = __builtin_amdgcn_mfma_f32_16x16x32_bf16(af.v, bfr[ni], acc[mi][ni], 0, 0, 0);
      }
    }
    __syncthreads();  // protect sK before next chunk's writes
  }
  // epilogue: D layout col(n=d)=lane&15, row(m=e)=quad*4+reg -> kvp[e][d]
  float* dst = kvp + (size_t)(s * 32 + bh) * (HD * HD);
#pragma unroll
  for (int mi = 0; mi < 4; ++mi) {
#pragma unroll
    for (int ni = 0; ni < 4; ++ni) {
#pragma unroll
      for (int rr = 0; rr < 4; ++rr) {
        const int e = e0 + mi * 16 + quad * 4 + rr;
        const int d = d0 + ni * 16 + row;
        dst[e * HD + d] = acc[mi][ni][rr];
      }
    }
  }
}

// ---------------- kv reduce: sum partials (already [e][d]), emit bf16 ---------
__global__ void kv_reduce_k(const float* __restrict__ kvp, unsigned short* __restrict__ kvtb) {
  int idx = blockIdx.x * 256 + threadIdx.x;  // 524288 = 32*128*128
  float ssum = 0.f;
#pragma unroll
  for (int i = 0; i < 16; ++i) ssum += kvp[(size_t)i * (32 * HD * HD) + idx];
  kvtb[idx] = f2bf(ssum * (1.0f / 9216.0f));
}

// ---------------- out (MFMA): out[b, head*128+e, pos] = z * sum_d qrope*kv ----
// m = e (A from kvtb[bh][e][d], k-contig), n = pos (B from rope(q), k-contig).
// No LDS; A/B frags read straight from global (kvtb is 1 MB, L2/L3-hot).
__launch_bounds__(256)
__global__ void out_mfma_k(const unsigned short* __restrict__ qbf,
                           const unsigned short* __restrict__ kvtb,
                           const float* __restrict__ z, const float* __restrict__ rope,
                           float* __restrict__ out) {
  const int bh = blockIdx.y, b = bh >> 2, head = bh & 3;
  const int pos0 = blockIdx.x * 128;
  const int tid = threadIdx.x, wv = tid >> 6, lane = tid & 63;
  const int row = lane & 15, quad = lane >> 4;
  const int e0 = (wv & 1) * 64;
  const int p0 = (wv >> 1) * 64;
  f32x4 acc[4][4];
#pragma unroll
  for (int mi = 0; mi < 4; ++mi)
#pragma unroll
    for (int ni = 0; ni < 4; ++ni) acc[mi][ni] = (f32x4){0.f, 0.f, 0.f, 0.f};

  int posn[4], coln[4];
#pragma unroll
  for (int ni = 0; ni < 4; ++ni) {
    posn[ni] = pos0 + p0 + ni * 16 + row;
    coln[ni] = posn[ni] % 96;
  }

#pragma unroll
  for (int kt = 0; kt < HD; kt += 32) {
    bf16x8 af[4], bfr[4];
#pragma unroll
    for (int mi = 0; mi < 4; ++mi)
      af[mi] = *(const bf16x8*)&kvtb[((size_t)bh * HD + e0 + mi * 16 + row) * HD + kt + quad * 8];
#pragma unroll
    for (int ni = 0; ni < 4; ++ni) {
      const uint4 u = *(const uint4*)(qbf + ((size_t)b * NN + posn[ni]) * CC +
                                      head * HD + kt + quad * 8);
      const int pairb = head * 64 + (kt >> 1) + quad * 4;
      const float* rp = rope + ((size_t)coln[ni] * KMAX + pairb) * 2;
      float4 r0 = *(const float4*)rp;        // c0 s0 c1 s1
      float4 r1 = *(const float4*)(rp + 4);  // c2 s2 c3 s3
      unsigned int uu[4] = {u.x, u.y, u.z, u.w};
      float cs[8] = {r0.x, r0.y, r0.z, r0.w, r1.x, r1.y, r1.z, r1.w};
      bf16x8 bb;
#pragma unroll
      for (int pr = 0; pr < 4; ++pr) {
        float re = bf2f((unsigned short)(uu[pr] & 0xffffu));
        float im = bf2f((unsigned short)(uu[pr] >> 16));
        float c = cs[2 * pr], s = cs[2 * pr + 1];
        bb[2 * pr] = (short)f2bf(c * re - s * im);
        bb[2 * pr + 1] = (short)f2bf(s * re + c * im);
      }
      bfr[ni] = bb;
    }
#pragma unroll
    for (int mi = 0; mi < 4; ++mi)
#pragma unroll
      for (int ni = 0; ni < 4; ++ni)
        acc[mi][ni] = __builtin_amdgcn_mfma_f32_16x16x32_bf16(af[mi], bfr[ni], acc[mi][ni], 0, 0, 0);
  }
  float zv[4];
#pragma unroll
  for (int ni = 0; ni < 4; ++ni) zv[ni] = z[(size_t)bh * NN + posn[ni]];
#pragma unroll
  for (int mi = 0; mi < 4; ++mi) {
#pragma unroll
    for (int ni = 0; ni < 4; ++ni) {
#pragma unroll
      for (int r = 0; r < 4; ++r) {
        int e = e0 + mi * 16 + quad * 4 + r;
        out[((size_t)b * CC + head * HD + e) * NN + posn[ni]] = acc[mi][ni][r] * zv[ni];
      }
    }
  }
}

// ---------------- lepe: depthwise 3x3 conv of x, ADDS into d_out --------------
// ILP-oriented: per thread 4 outputs from 3 rows x (float4 + 2 edge scalars);
// round-2 version was latency-bound at VGPR=8 (36 dependent scalar loads).
__global__ void lepe_k(const float* __restrict__ x, const float* __restrict__ lw,
                       const float* __restrict__ lb, float* __restrict__ out) {
  const int blk = blockIdx.x;  // B*C*9
  const int bc = blk / 9;
  const int tile = blk - bc * 9;
  const int ch = bc & (CC - 1);
  const float* wp = lw + ch * 9;
  float w[9];
#pragma unroll
  for (int t = 0; t < 9; ++t) w[t] = wp[t];
  const float bias = lb[ch];
  const float* xp = x + (size_t)bc * NN;
  const int pos = tile * 1024 + threadIdx.x * 4;
  const int pi = pos / 96;
  const int pj = pos - pi * 96;  // multiple of 4

  float4 o = *(const float4*)(out + (size_t)bc * NN + pos);  // RMW read early

  float a0 = bias, a1 = bias, a2 = bias, a3 = bias;
#pragma unroll
  for (int r = 0; r < 3; ++r) {
    const int y = pi + r - 1;
    if ((unsigned)y >= 96u) continue;
    const float* rowp = xp + y * 96 + pj;
    float4 M = *(const float4*)rowp;
    float Lv = (pj > 0) ? rowp[-1] : 0.f;
    float Rv = (pj < 92) ? rowp[4] : 0.f;
    const float w0 = w[r * 3 + 0], w1 = w[r * 3 + 1], w2 = w[r * 3 + 2];
    a0 += w0 * Lv + w1 * M.x + w2 * M.y;
    a1 += w0 * M.x + w1 * M.y + w2 * M.z;
    a2 += w0 * M.y + w1 * M.z + w2 * M.w;
    a3 += w0 * M.z + w1 * M.w + w2 * Rv;
  }
  o.x += a0; o.y += a1; o.z += a2; o.w += a3;
  *(float4*)(out + (size_t)bc * NN + pos) = o;
}

extern "C" void kernel_launch(void* const* d_in, const int* in_sizes, int n_in,
                              void* d_out, int out_size, void* d_ws, size_t ws_size,
                              hipStream_t stream) {
  const float* x = (const float*)d_in[0];
  const float* Wqk = (const float*)d_in[1];
  const float* bqk = (const float*)d_in[2];
  const float* lw = (const float*)d_in[3];
  const float* lb = (const float*)d_in[4];
  float* out = (float*)d_out;
  char* ws = (char*)d_ws;
  // ws layout (≈189 MB peak; xtb + kmean partials overlay the kvp region,
  // which is only live from kv_mfma_k onward; kvtb overlays old kv slot):
  unsigned short* qbf = (unsigned short*)(ws);                 // 75,497,472 B
  unsigned short* kbf = (unsigned short*)(ws + 75497472);      // 75,497,472 B
  float* rope = (float*)(ws + 150994944);                      //    196,608 B
  float* kmean = (float*)(ws + 151191552);                     //     16,384 B
  float* z = (float*)(ws + 151207936);                         //  1,179,648 B
  float* kvp = (float*)(ws + 152387584);                       // 33,554,432 B
  unsigned short* xtb = (unsigned short*)(ws + 152387584);     //  9,437,184 B (overlay)
  float* kmean_part = (float*)(ws + 152387584 + 16777216);     //    294,912 B (overlay)
  unsigned short* kvtb = (unsigned short*)(ws + 185942016);    //  1,048,576 B
  unsigned short* Wbf = (unsigned short*)(ws + 188039168);     //  1,048,576 B

  conv_w_k<<<dim3(512), dim3(256), 0, stream>>>(Wqk, Wbf);
  rope_table_k<<<dim3(96), dim3(256), 0, stream>>>(rope);
  for (int b = 0; b < BB; ++b) {
    transpose_xb_k<<<dim3(144, 8), dim3(256), 0, stream>>>(x, xtb, b);
    gemm_qk_mfma<<<dim3(8, 72), dim3(256), 0, stream>>>(xtb, Wbf, bqk, qbf, kbf, b);
  }
  kmean_p1_k<<<dim3(18, 32), dim3(256), 0, stream>>>(kbf, kmean_part);
  kmean_p2_k<<<dim3(16), dim3(256), 0, stream>>>(kmean_part, kmean);
  z_k<<<dim3(9216), dim3(256), 0, stream>>>(qbf, kmean, z);
  kv_mfma_k<<<dim3(16, 32), dim3(256), 0, stream>>>(kbf, x, rope, kvp);
  kv_reduce_k<<<dim3(2048), dim3(256), 0, stream>>>(kvp, kvtb);
  out_mfma_k<<<dim3(72, 32), dim3(256), 0, stream>>>(qbf, kvtb, z, rope, out);
  lepe_k<<<dim3(36864), dim3(256), 0, stream>>>(x, lw, lb, out);
}